// Round 1
// baseline (150.694 us; speedup 1.0000x reference)
//
#include <hip/hip_runtime.h>
#include <math.h>

// AcidSynth: time-varying biquad as a parallel affine scan.
// s[t] = A_t s[t-1] + d_t,  A_t = [[-a1,1],[-a2,0]] (companion structure).
// 3 kernels: per-chunk compose -> single-block scan of chunk transforms ->
// per-chunk replay + tanh. Chunk L=32, G=N/32=16384 chunks.

#define LCHUNK 32

struct Aff { float m00,m01,m10,m11,c0,c1; };

__device__ __forceinline__ Aff aff_identity(){ return Aff{1.f,0.f,0.f,1.f,0.f,0.f}; }

// returns B∘A (A applied first)
__device__ __forceinline__ Aff aff_compose(const Aff& B, const Aff& A){
  Aff r;
  r.m00 = fmaf(B.m00, A.m00, B.m01*A.m10);
  r.m01 = fmaf(B.m00, A.m01, B.m01*A.m11);
  r.m10 = fmaf(B.m10, A.m00, B.m11*A.m10);
  r.m11 = fmaf(B.m10, A.m01, B.m11*A.m11);
  r.c0  = fmaf(B.m00, A.c0, fmaf(B.m01, A.c1, B.c0));
  r.c1  = fmaf(B.m10, A.c0, fmaf(B.m11, A.c1, B.c1));
  return r;
}

__device__ __forceinline__ Aff aff_shfl_up(const Aff& a, int delta){
  Aff r;
  r.m00 = __shfl_up(a.m00, delta, 64);
  r.m01 = __shfl_up(a.m01, delta, 64);
  r.m10 = __shfl_up(a.m10, delta, 64);
  r.m11 = __shfl_up(a.m11, delta, 64);
  r.c0  = __shfl_up(a.c0 , delta, 64);
  r.c1  = __shfl_up(a.c1 , delta, 64);
  return r;
}

// RBJ lowpass coefficients; na1 = -a1, na2 = -a2 (normalized), b2 == b0, b1 == 2*b0.
// rev = w0/(2pi) = w_hz/SR directly -> feeds v_sin/v_cos (revolution input).
__device__ __forceinline__ void coefs(float wv, float qv,
                                      float& na1, float& na2, float& b0, float& b1){
  float rev = fmaf(wv, 7900.0f/48000.0f, 100.0f/48000.0f);
  float cw = __builtin_amdgcn_cosf(rev);
  float sw = __builtin_amdgcn_sinf(rev);
  float qq = fmaf(qv, 8.0f - 0.7071f, 0.7071f);
  float af = sw * (0.5f * __builtin_amdgcn_rcpf(qq));
  float ia = __builtin_amdgcn_rcpf(1.0f + af);
  float t1 = 1.0f - cw;
  b1 = t1 * ia;
  b0 = 0.5f * b1;
  na1 = (cw + cw) * ia;
  na2 = (af - 1.0f) * ia;
}

__device__ __forceinline__ void get_controls(const float* midi01, const float* alpha01,
                                             const float* phasep,
                                             float& alpha, float& f0c, float& phase0){
  #pragma clang fp contract(off)
  alpha = alpha01[0]*2.8f + 0.2f;
  float md = rintf(midi01[0]*30.0f + 30.0f);          // np.round: half-even
  float f0 = 440.0f * exp2f((md - 69.0f)/12.0f);
  f0c = 6.2831855f * f0;                              // 2*pi*f0 in f32, ref op order
  phase0 = phasep[0];
}

// dry[i] = 0.5*sq*env; replicate reference f32 op order (no contraction) to keep
// the square-wave sign decision bit-faithful.
__device__ __forceinline__ float osc_dry(int i, float alpha, float f0c, float phase0){
  #pragma clang fp contract(off)
  float tf = (float)i;
  float u = 1.0f - tf/6000.0f;                        // NOTE_ON_DUR*SR = 6000
  u = fminf(fmaxf(u, 0.0f), 1.0f);
  float env = powf(u, alpha);
  float arg = phase0 + (f0c*tf)/48000.0f;
  float d = arg/6.2831855f;
  float m = d - floorf(d);
  float sq = (m < 0.5f) ? 1.0f : -1.0f;
  return (0.5f*sq)*env;
}

// ---------------- pass 1: per-chunk transform composition ----------------
__global__ __launch_bounds__(256) void k_chunk(const float* __restrict__ w,
    const float* __restrict__ qm, const float* __restrict__ midi01,
    const float* __restrict__ alpha01, const float* __restrict__ phasep,
    float* __restrict__ Tm){
  const int g = blockIdx.x*256 + threadIdx.x;
  const int base = g * LCHUNK;
  float m00=1.f, m01=0.f, m10=0.f, m11=1.f, c0=0.f, c1=0.f;
  const bool has_dry = (base < 6000);
  float alpha=0.f, f0c=0.f, phase0=0.f;
  if (has_dry) get_controls(midi01, alpha01, phasep, alpha, f0c, phase0);
  const float4* w4p = reinterpret_cast<const float4*>(w + base);
  const float4* q4p = reinterpret_cast<const float4*>(qm + base);
  #pragma unroll
  for (int j=0;j<LCHUNK/4;j++){
    float4 w4 = w4p[j];
    float4 q4 = q4p[j];
    #pragma unroll
    for (int e=0;e<4;e++){
      float wvv = (&w4.x)[e];
      float qvv = (&q4.x)[e];
      float na1,na2,b0,b1;
      coefs(wvv,qvv,na1,na2,b0,b1);
      float nm00 = fmaf(na1, m00, m10);
      float nm01 = fmaf(na1, m01, m11);
      m10 = na2*m00; m11 = na2*m01;
      m00 = nm00;   m01 = nm01;
      float nc0 = fmaf(na1, c0, c1);
      float nc1 = na2*c0;
      if (has_dry){
        float x = osc_dry(base + j*4 + e, alpha, f0c, phase0);
        nc0 = fmaf(fmaf(na1,b0,b1), x, nc0);   // d0 = (b1 - a1*b0)*x
        nc1 = fmaf(fmaf(na2,b0,b0), x, nc1);   // d1 = (b2 - a2*b0)*x, b2==b0
      }
      c0 = nc0; c1 = nc1;
    }
  }
  reinterpret_cast<float4*>(Tm)[g*2+0] = make_float4(m00,m01,m10,m11);
  reinterpret_cast<float4*>(Tm)[g*2+1] = make_float4(c0,c1,0.f,0.f);
}

// ---------------- pass 2: single-block scan over G chunk transforms ----------------
__global__ __launch_bounds__(1024) void k_scan(const float* __restrict__ Tm,
    const float* __restrict__ zi, float2* __restrict__ St, int K){
  const int tid  = threadIdx.x;
  const int lane = tid & 63;
  const int wv   = tid >> 6;
  const float4* T4 = reinterpret_cast<const float4*>(Tm);
  Aff T = aff_identity();
  for (int k=0;k<K;k++){
    int gg = tid*K + k;
    float4 A4 = T4[gg*2+0];
    float4 B4 = T4[gg*2+1];
    Aff A{A4.x,A4.y,A4.z,A4.w,B4.x,B4.y};
    T = aff_compose(A, T);
  }
  // inclusive scan within wave
  #pragma unroll
  for (int off=1; off<64; off<<=1){
    Aff P = aff_shfl_up(T, off);
    if (lane >= off) T = aff_compose(T, P);
  }
  __shared__ float tot[16][6];
  __shared__ float tots[16][6];
  if (lane == 63){
    tot[wv][0]=T.m00; tot[wv][1]=T.m01; tot[wv][2]=T.m10;
    tot[wv][3]=T.m11; tot[wv][4]=T.c0;  tot[wv][5]=T.c1;
  }
  __syncthreads();
  if (wv == 0 && lane < 16){
    Aff W{tot[lane][0],tot[lane][1],tot[lane][2],tot[lane][3],tot[lane][4],tot[lane][5]};
    #pragma unroll
    for (int off=1; off<16; off<<=1){
      Aff P = aff_shfl_up(W, off);
      if (lane >= off) W = aff_compose(W, P);
    }
    tots[lane][0]=W.m00; tots[lane][1]=W.m01; tots[lane][2]=W.m10;
    tots[lane][3]=W.m11; tots[lane][4]=W.c0;  tots[lane][5]=W.c1;
  }
  __syncthreads();
  Aff E = aff_shfl_up(T, 1);
  if (lane == 0) E = aff_identity();
  if (wv > 0){
    Aff Wp{tots[wv-1][0],tots[wv-1][1],tots[wv-1][2],tots[wv-1][3],tots[wv-1][4],tots[wv-1][5]};
    E = aff_compose(E, Wp);
  }
  float z0 = zi[0], z1 = zi[1];
  float s0 = fmaf(E.m00, z0, fmaf(E.m01, z1, E.c0));
  float s1 = fmaf(E.m10, z0, fmaf(E.m11, z1, E.c1));
  for (int k=0;k<K;k++){
    int gg = tid*K + k;
    St[gg] = make_float2(s0, s1);
    float4 A4 = T4[gg*2+0];
    float4 B4 = T4[gg*2+1];
    float ns0 = fmaf(A4.x, s0, fmaf(A4.y, s1, B4.x));
    float ns1 = fmaf(A4.z, s0, fmaf(A4.w, s1, B4.y));
    s0 = ns0; s1 = ns1;
  }
}

// ---------------- pass 3: replay each chunk from its entry state ----------------
__global__ __launch_bounds__(256) void k_apply(const float* __restrict__ w,
    const float* __restrict__ qm, const float* __restrict__ midi01,
    const float* __restrict__ alpha01, const float* __restrict__ phasep,
    const float2* __restrict__ St, float* __restrict__ out){
  const int g = blockIdx.x*256 + threadIdx.x;
  const int base = g * LCHUNK;
  float2 s = St[g];
  float u1 = s.x, u2 = s.y;
  const bool has_dry = (base < 6000);
  float alpha=0.f, f0c=0.f, phase0=0.f;
  if (has_dry) get_controls(midi01, alpha01, phasep, alpha, f0c, phase0);
  const float4* w4p = reinterpret_cast<const float4*>(w + base);
  const float4* q4p = reinterpret_cast<const float4*>(qm + base);
  float4* o4p = reinterpret_cast<float4*>(out + base);
  #pragma unroll
  for (int j=0;j<LCHUNK/4;j++){
    float4 w4 = w4p[j];
    float4 q4 = q4p[j];
    float4 ov;
    #pragma unroll
    for (int e=0;e<4;e++){
      float wvv = (&w4.x)[e];
      float qvv = (&q4.x)[e];
      float na1,na2,b0,b1;
      coefs(wvv,qvv,na1,na2,b0,b1);
      float x = 0.0f;
      if (has_dry) x = osc_dry(base + j*4 + e, alpha, f0c, phase0);
      float y = fmaf(b0, x, u1);                      // y = b0*x + s1
      float nu1 = fmaf(b1, x, fmaf(na1, y, u2));      // s1' = b1*x - a1*y + s2
      float nu2 = fmaf(b0, x, na2*y);                 // s2' = b2*x - a2*y, b2==b0
      u1 = nu1; u2 = nu2;
      // tanh(y) = 1 - 2/(exp(2y)+1); exp overflow/underflow saturate correctly
      float ey = __expf(y + y);
      float r = __builtin_amdgcn_rcpf(ey + 1.0f);
      (&ov.x)[e] = fmaf(-2.0f, r, 1.0f);
    }
    o4p[j] = ov;
  }
}

// ---------------- fallback: fully sequential (only if ws too small) ----------------
__global__ void k_naive(const float* __restrict__ w, const float* __restrict__ qm,
    const float* __restrict__ midi01, const float* __restrict__ alpha01,
    const float* __restrict__ phasep, const float* __restrict__ zi,
    float* __restrict__ out, int n){
  if (blockIdx.x != 0 || threadIdx.x != 0) return;
  float alpha,f0c,phase0; get_controls(midi01, alpha01, phasep, alpha, f0c, phase0);
  float u1 = zi[0], u2 = zi[1];
  for (int i=0;i<n;i++){
    float na1,na2,b0,b1;
    coefs(w[i], qm[i], na1,na2,b0,b1);
    float x = (i < 6000) ? osc_dry(i, alpha, f0c, phase0) : 0.0f;
    float y = fmaf(b0, x, u1);
    float nu1 = fmaf(b1, x, fmaf(na1, y, u2));
    float nu2 = fmaf(b0, x, na2*y);
    u1 = nu1; u2 = nu2;
    float ey = __expf(y + y);
    float r = __builtin_amdgcn_rcpf(ey + 1.0f);
    out[i] = fmaf(-2.0f, r, 1.0f);
  }
}

extern "C" void kernel_launch(void* const* d_in, const int* in_sizes, int n_in,
                              void* d_out, int out_size, void* d_ws, size_t ws_size,
                              hipStream_t stream) {
  const float* midi01  = (const float*)d_in[1];
  const float* alpha01 = (const float*)d_in[2];
  const float* w       = (const float*)d_in[3];
  const float* qm      = (const float*)d_in[4];
  const float* ph      = (const float*)d_in[5];
  const float* zi      = (const float*)d_in[6];
  float* out = (float*)d_out;
  const int n = in_sizes[0];                    // 524288
  const int G = n / LCHUNK;                     // 16384 chunks
  const size_t tm_bytes = (size_t)G * 8 * sizeof(float);
  const size_t need = tm_bytes + (size_t)G * sizeof(float2);

  if ((n % LCHUNK) != 0 || (G % 1024) != 0 || ws_size < need) {
    k_naive<<<1, 64, 0, stream>>>(w, qm, midi01, alpha01, ph, zi, out, n);
    return;
  }
  float*  Tm = (float*)d_ws;
  float2* St = (float2*)((char*)d_ws + tm_bytes);
  const int K = G / 1024;

  k_chunk<<<dim3(G/256), dim3(256), 0, stream>>>(w, qm, midi01, alpha01, ph, Tm);
  k_scan <<<dim3(1),     dim3(1024), 0, stream>>>(Tm, zi, St, K);
  k_apply<<<dim3(G/256), dim3(256), 0, stream>>>(w, qm, midi01, alpha01, ph, St, out);
}

// Round 2
// 87.746 us; speedup vs baseline: 1.7174x; 1.7174x over previous
//
#include <hip/hip_runtime.h>
#include <math.h>

// AcidSynth: time-varying biquad as a hierarchical parallel affine scan.
// s[t] = A_t s[t-1] + d_t,  A_t = [[-a1,1],[-a2,0]] (companion structure).
// k_pass1: per-thread 16-sample chunk transform + block-level scan (256 chunks)
//          -> per-chunk exclusive-prefix affine (Pf) + per-block total (Bt).
// k_pass2: every block redundantly scans the 128 block totals (3 KB, L2) to get
//          its entry state, applies per-chunk prefix, replays 16 samples + tanh.

#define LCHUNK 16

struct Aff { float m00,m01,m10,m11,c0,c1; };

__device__ __forceinline__ Aff aff_identity(){ return Aff{1.f,0.f,0.f,1.f,0.f,0.f}; }

// returns B∘A (A applied first)
__device__ __forceinline__ Aff aff_compose(const Aff& B, const Aff& A){
  Aff r;
  r.m00 = fmaf(B.m00, A.m00, B.m01*A.m10);
  r.m01 = fmaf(B.m00, A.m01, B.m01*A.m11);
  r.m10 = fmaf(B.m10, A.m00, B.m11*A.m10);
  r.m11 = fmaf(B.m10, A.m01, B.m11*A.m11);
  r.c0  = fmaf(B.m00, A.c0, fmaf(B.m01, A.c1, B.c0));
  r.c1  = fmaf(B.m10, A.c0, fmaf(B.m11, A.c1, B.c1));
  return r;
}

__device__ __forceinline__ Aff aff_shfl_up(const Aff& a, int delta){
  Aff r;
  r.m00 = __shfl_up(a.m00, delta, 64);
  r.m01 = __shfl_up(a.m01, delta, 64);
  r.m10 = __shfl_up(a.m10, delta, 64);
  r.m11 = __shfl_up(a.m11, delta, 64);
  r.c0  = __shfl_up(a.c0 , delta, 64);
  r.c1  = __shfl_up(a.c1 , delta, 64);
  return r;
}

// RBJ lowpass coefficients; na1 = -a1, na2 = -a2 (normalized), b2 == b0, b1 == 2*b0.
__device__ __forceinline__ void coefs(float wv, float qv,
                                      float& na1, float& na2, float& b0, float& b1){
  float rev = fmaf(wv, 7900.0f/48000.0f, 100.0f/48000.0f);
  float cw = __builtin_amdgcn_cosf(rev);
  float sw = __builtin_amdgcn_sinf(rev);
  float qq = fmaf(qv, 8.0f - 0.7071f, 0.7071f);
  float af = sw * (0.5f * __builtin_amdgcn_rcpf(qq));
  float ia = __builtin_amdgcn_rcpf(1.0f + af);
  float t1 = 1.0f - cw;
  b1 = t1 * ia;
  b0 = 0.5f * b1;
  na1 = (cw + cw) * ia;
  na2 = (af - 1.0f) * ia;
}

__device__ __forceinline__ void get_controls(const float* midi01, const float* alpha01,
                                             const float* phasep,
                                             float& alpha, float& f0c, float& phase0){
  #pragma clang fp contract(off)
  alpha = alpha01[0]*2.8f + 0.2f;
  float md = rintf(midi01[0]*30.0f + 30.0f);          // np.round: half-even
  float f0 = 440.0f * exp2f((md - 69.0f)/12.0f);
  f0c = 6.2831855f * f0;                              // 2*pi*f0 in f32, ref op order
  phase0 = phasep[0];
}

// dry[i] = 0.5*sq*env; replicate reference f32 op order (no contraction) to keep
// the square-wave sign decision bit-faithful.
__device__ __forceinline__ float osc_dry(int i, float alpha, float f0c, float phase0){
  #pragma clang fp contract(off)
  float tf = (float)i;
  float u = 1.0f - tf/6000.0f;                        // NOTE_ON_DUR*SR = 6000
  u = fminf(fmaxf(u, 0.0f), 1.0f);
  float env = powf(u, alpha);
  float arg = phase0 + (f0c*tf)/48000.0f;
  float d = arg/6.2831855f;
  float m = d - floorf(d);
  float sq = (m < 0.5f) ? 1.0f : -1.0f;
  return (0.5f*sq)*env;
}

// ---------------- pass 1: chunk transforms + block-level scan ----------------
__global__ __launch_bounds__(256) void k_pass1(const float* __restrict__ w,
    const float* __restrict__ qm, const float* __restrict__ midi01,
    const float* __restrict__ alpha01, const float* __restrict__ phasep,
    float4* __restrict__ Pf4, float2* __restrict__ Pf2, float4* __restrict__ Bt){
  const int tid = threadIdx.x;
  const int g = blockIdx.x*256 + tid;
  const int base = g * LCHUNK;
  float m00=1.f, m01=0.f, m10=0.f, m11=1.f, c0=0.f, c1=0.f;
  const bool has_dry = (base < 6000);
  float alpha=0.f, f0c=0.f, phase0=0.f;
  if (has_dry) get_controls(midi01, alpha01, phasep, alpha, f0c, phase0);
  const float4* w4p = reinterpret_cast<const float4*>(w + base);
  const float4* q4p = reinterpret_cast<const float4*>(qm + base);
  #pragma unroll
  for (int j=0;j<LCHUNK/4;j++){
    float4 w4 = w4p[j];
    float4 q4 = q4p[j];
    #pragma unroll
    for (int e=0;e<4;e++){
      float na1,na2,b0,b1;
      coefs((&w4.x)[e], (&q4.x)[e], na1,na2,b0,b1);
      float nm00 = fmaf(na1, m00, m10);
      float nm01 = fmaf(na1, m01, m11);
      m10 = na2*m00; m11 = na2*m01;
      m00 = nm00;   m01 = nm01;
      float nc0 = fmaf(na1, c0, c1);
      float nc1 = na2*c0;
      if (has_dry){
        float x = osc_dry(base + j*4 + e, alpha, f0c, phase0);
        nc0 = fmaf(fmaf(na1,b0,b1), x, nc0);   // d0 = (b1 - a1*b0)*x
        nc1 = fmaf(fmaf(na2,b0,b0), x, nc1);   // d1 = (b2 - a2*b0)*x, b2==b0
      }
      c0 = nc0; c1 = nc1;
    }
  }
  // block-level scan over the 256 chunk transforms
  const int lane = tid & 63, wv = tid >> 6;
  Aff Tin{m00,m01,m10,m11,c0,c1};
  #pragma unroll
  for (int off=1; off<64; off<<=1){
    Aff P = aff_shfl_up(Tin, off);
    if (lane >= off) Tin = aff_compose(Tin, P);
  }
  __shared__ float wt[4][6];
  if (lane == 63){
    wt[wv][0]=Tin.m00; wt[wv][1]=Tin.m01; wt[wv][2]=Tin.m10;
    wt[wv][3]=Tin.m11; wt[wv][4]=Tin.c0;  wt[wv][5]=Tin.c1;
  }
  __syncthreads();
  Aff Wp = aff_identity();
  for (int j=0;j<wv;j++){
    Aff Wj{wt[j][0],wt[j][1],wt[j][2],wt[j][3],wt[j][4],wt[j][5]};
    Wp = aff_compose(Wj, Wp);
  }
  Aff Ex = aff_shfl_up(Tin, 1);
  if (lane == 0) Ex = aff_identity();
  Aff Epre = aff_compose(Ex, Wp);      // exclusive prefix within block
  Pf4[g] = make_float4(Epre.m00, Epre.m01, Epre.m10, Epre.m11);
  Pf2[g] = make_float2(Epre.c0, Epre.c1);
  if (tid == 255){
    Aff Full = aff_compose(Tin, Wp);   // block total
    Bt[blockIdx.x*2+0] = make_float4(Full.m00, Full.m01, Full.m10, Full.m11);
    Bt[blockIdx.x*2+1] = make_float4(Full.c0, Full.c1, 0.f, 0.f);
  }
}

// ---------------- pass 2: redundant tiny scan + replay ----------------
__global__ __launch_bounds__(256) void k_pass2(const float* __restrict__ w,
    const float* __restrict__ qm, const float* __restrict__ midi01,
    const float* __restrict__ alpha01, const float* __restrict__ phasep,
    const float* __restrict__ zi,
    const float4* __restrict__ Pf4, const float2* __restrict__ Pf2,
    const float4* __restrict__ Bt, float* __restrict__ out, int B){
  const int tid = threadIdx.x;
  const int blk = blockIdx.x;
  const int lane = tid & 63;
  __shared__ float2 stsh[128];
  __shared__ float wtot[6];
  const float z0 = zi[0], z1 = zi[1];
  // threads 0..127 (2 waves) scan the B<=128 block totals
  if (tid < 128){
    Aff T = aff_identity();
    if (tid < B){
      float4 A4 = Bt[tid*2+0];
      float4 C4 = Bt[tid*2+1];
      T = Aff{A4.x,A4.y,A4.z,A4.w,C4.x,C4.y};
    }
    #pragma unroll
    for (int off=1; off<64; off<<=1){
      Aff P = aff_shfl_up(T, off);
      if (lane >= off) T = aff_compose(T, P);
    }
    if (tid == 63){
      wtot[0]=T.m00; wtot[1]=T.m01; wtot[2]=T.m10;
      wtot[3]=T.m11; wtot[4]=T.c0;  wtot[5]=T.c1;
    }
    __syncthreads();
    if (tid >= 64){
      Aff W0{wtot[0],wtot[1],wtot[2],wtot[3],wtot[4],wtot[5]};
      T = aff_compose(T, W0);
    }
    float s0 = fmaf(T.m00, z0, fmaf(T.m01, z1, T.c0));
    float s1 = fmaf(T.m10, z0, fmaf(T.m11, z1, T.c1));
    stsh[tid] = make_float2(s0, s1);
  } else {
    __syncthreads();
  }
  __syncthreads();
  const float2 e = (blk == 0) ? make_float2(z0, z1) : stsh[blk-1];
  // own chunk entry state
  const int g = blk*256 + tid;
  const int base = g * LCHUNK;
  float4 P4 = Pf4[g];
  float2 P2 = Pf2[g];
  float u1 = fmaf(P4.x, e.x, fmaf(P4.y, e.y, P2.x));
  float u2 = fmaf(P4.z, e.x, fmaf(P4.w, e.y, P2.y));
  const bool has_dry = (base < 6000);
  float alpha=0.f, f0c=0.f, phase0=0.f;
  if (has_dry) get_controls(midi01, alpha01, phasep, alpha, f0c, phase0);
  const float4* w4p = reinterpret_cast<const float4*>(w + base);
  const float4* q4p = reinterpret_cast<const float4*>(qm + base);
  float4* o4p = reinterpret_cast<float4*>(out + base);
  #pragma unroll
  for (int j=0;j<LCHUNK/4;j++){
    float4 w4 = w4p[j];
    float4 q4 = q4p[j];
    float4 ov;
    #pragma unroll
    for (int ecnt=0;ecnt<4;ecnt++){
      float na1,na2,b0,b1;
      coefs((&w4.x)[ecnt], (&q4.x)[ecnt], na1,na2,b0,b1);
      float x = 0.0f;
      if (has_dry) x = osc_dry(base + j*4 + ecnt, alpha, f0c, phase0);
      float y = fmaf(b0, x, u1);                      // y = b0*x + s1
      float nu1 = fmaf(b1, x, fmaf(na1, y, u2));      // s1' = b1*x - a1*y + s2
      float nu2 = fmaf(b0, x, na2*y);                 // s2' = b2*x - a2*y, b2==b0
      u1 = nu1; u2 = nu2;
      // tanh(y) = 1 - 2/(exp(2y)+1)
      float ey = __expf(y + y);
      float r = __builtin_amdgcn_rcpf(ey + 1.0f);
      (&ov.x)[ecnt] = fmaf(-2.0f, r, 1.0f);
    }
    o4p[j] = ov;
  }
}

// ---------------- fallback: fully sequential (only if shapes/ws mismatch) ----------------
__global__ void k_naive(const float* __restrict__ w, const float* __restrict__ qm,
    const float* __restrict__ midi01, const float* __restrict__ alpha01,
    const float* __restrict__ phasep, const float* __restrict__ zi,
    float* __restrict__ out, int n){
  if (blockIdx.x != 0 || threadIdx.x != 0) return;
  float alpha,f0c,phase0; get_controls(midi01, alpha01, phasep, alpha, f0c, phase0);
  float u1 = zi[0], u2 = zi[1];
  for (int i=0;i<n;i++){
    float na1,na2,b0,b1;
    coefs(w[i], qm[i], na1,na2,b0,b1);
    float x = (i < 6000) ? osc_dry(i, alpha, f0c, phase0) : 0.0f;
    float y = fmaf(b0, x, u1);
    float nu1 = fmaf(b1, x, fmaf(na1, y, u2));
    float nu2 = fmaf(b0, x, na2*y);
    u1 = nu1; u2 = nu2;
    float ey = __expf(y + y);
    float r = __builtin_amdgcn_rcpf(ey + 1.0f);
    out[i] = fmaf(-2.0f, r, 1.0f);
  }
}

extern "C" void kernel_launch(void* const* d_in, const int* in_sizes, int n_in,
                              void* d_out, int out_size, void* d_ws, size_t ws_size,
                              hipStream_t stream) {
  const float* midi01  = (const float*)d_in[1];
  const float* alpha01 = (const float*)d_in[2];
  const float* w       = (const float*)d_in[3];
  const float* qm      = (const float*)d_in[4];
  const float* ph      = (const float*)d_in[5];
  const float* zi      = (const float*)d_in[6];
  float* out = (float*)d_out;
  const int n = in_sizes[0];                    // 524288
  const int G = n / LCHUNK;                     // 32768 chunks
  const int B = G / 256;                        // 128 blocks
  const size_t pf4_bytes = (size_t)G * sizeof(float4);
  const size_t pf2_bytes = (size_t)G * sizeof(float2);
  const size_t bt_bytes  = (size_t)B * 2 * sizeof(float4);
  const size_t need = pf4_bytes + pf2_bytes + bt_bytes;

  if ((n % LCHUNK) != 0 || (G % 256) != 0 || B > 128 || ws_size < need) {
    k_naive<<<1, 64, 0, stream>>>(w, qm, midi01, alpha01, ph, zi, out, n);
    return;
  }
  float4* Pf4 = (float4*)d_ws;
  float2* Pf2 = (float2*)((char*)d_ws + pf4_bytes);
  float4* Bt  = (float4*)((char*)d_ws + pf4_bytes + pf2_bytes);

  k_pass1<<<dim3(B), dim3(256), 0, stream>>>(w, qm, midi01, alpha01, ph, Pf4, Pf2, Bt);
  k_pass2<<<dim3(B), dim3(256), 0, stream>>>(w, qm, midi01, alpha01, ph, zi,
                                             Pf4, Pf2, Bt, out, B);
}